// Round 1
// baseline (161.601 us; speedup 1.0000x reference)
//
#include <hip/hip_runtime.h>
#include <math.h>

#define SEQ 512
#define HID 256
#define NH 8
#define DH 32
#define PI_F 3.14159265358979323846f
#define SCALE_F 0.17677669529663687f  /* 1/sqrt(32) */

// ws layout (floats):
//   omega : [SEQ*HID]  @ 0
//   amp   : [SEQ*HID]  @ 131072
//   vbuf  : [SEQ*HID]  @ 262144
//   phase : [SEQ*HID]  @ 393216
//   ctx   : [SEQ*HID]  @ 524288
// total 5*131072*4 = 2.62 MB

// ---------------- QKV projection + activations ----------------
// grid (SEQ/16, 3), block 256. blockIdx.y selects {q,k,v}.
// out[i,c] = sum_k x[i,k] * W[c,k] + b[c]   (nn.Linear: x @ W.T + b)
__global__ void proj_qkv(const float* __restrict__ x,
                         const float* __restrict__ wq, const float* __restrict__ bq,
                         const float* __restrict__ wk, const float* __restrict__ bk,
                         const float* __restrict__ wv, const float* __restrict__ bv,
                         float* __restrict__ ws) {
    const int which = blockIdx.y;
    const float* W;
    const float* bias;
    if (which == 0)      { W = wq; bias = bq; }
    else if (which == 1) { W = wk; bias = bk; }
    else                 { W = wv; bias = bv; }

    const int r0 = blockIdx.x * 16;
    __shared__ float xs[16][HID];
    for (int idx = threadIdx.x; idx < 16 * HID; idx += 256) {
        int r = idx >> 8;
        int k = idx & 255;
        xs[r][k] = x[(r0 + r) * HID + k];
    }
    __syncthreads();

    const int c = threadIdx.x;  // output column 0..255
    float acc[16];
#pragma unroll
    for (int r = 0; r < 16; r++) acc[r] = 0.f;

    const float4* wrow4 = reinterpret_cast<const float4*>(W + c * HID);
    for (int k4 = 0; k4 < HID / 4; k4++) {
        float4 w4 = wrow4[k4];
        const int k = 4 * k4;
#pragma unroll
        for (int r = 0; r < 16; r++) {
            acc[r] = fmaf(xs[r][k + 0], w4.x, acc[r]);
            acc[r] = fmaf(xs[r][k + 1], w4.y, acc[r]);
            acc[r] = fmaf(xs[r][k + 2], w4.z, acc[r]);
            acc[r] = fmaf(xs[r][k + 3], w4.w, acc[r]);
        }
    }

    const float b = bias[c];
    float* omega = ws;
    float* amp   = ws + 131072;
    float* vbuf  = ws + 262144;
    float* phase = ws + 393216;

#pragma unroll
    for (int r = 0; r < 16; r++) {
        float val = acc[r] + b;
        int o = (r0 + r) * HID + c;
        if (which == 0) {
            // omega = sigmoid(q) * pi   (precise expf: errors in omega get x511)
            omega[o] = PI_F / (1.f + expf(-val));
        } else if (which == 1) {
            amp[o] = 1.f / (1.f + expf(-val));
        } else {
            vbuf[o]  = val;
            phase[o] = PI_F * tanhf(val);
        }
    }
}

// ---------------- wave-interference attention ----------------
// grid (SEQ/8, NH), block 256: thread = (i_local = t>>5, d = t&31).
// Each thread owns one (i,d): full softmax over j and contraction with v[:,d].
__global__ void wave_attn(const float* __restrict__ ws_in, float* __restrict__ ctx) {
    const float* omega = ws_in;
    const float* amp   = ws_in + 131072;
    const float* vbuf  = ws_in + 262144;
    const float* phase = ws_in + 393216;

    const int h  = blockIdx.y;
    const int il = threadIdx.x >> 5;
    const int d  = threadIdx.x & 31;
    const int i  = blockIdx.x * 8 + il;
    const int col = h * DH + d;

    const float w  = omega[i * HID + col];
    const float a  = amp[i * HID + col] * SCALE_F;
    const float ph = phase[i * HID + col];

    const float* vcol = vbuf + col;

    float denom = 0.f;
    float numer = 0.f;
#pragma unroll 4
    for (int j = 0; j < SEQ; j++) {
        float n = (float)(i - j);
        float angle = fmaf(w, n, ph);
        float cn = __cosf(angle);
        float e  = __expf(a * cn);
        denom += e;
        numer = fmaf(e, vcol[j * HID], numer);
    }
    ctx[i * HID + col] = numer / denom;
}

// ---------------- output projection ----------------
// out[i,c] = sum_k ctx[i,k] * wo[c,k] + bo[c]
__global__ void proj_out(const float* __restrict__ ctx, const float* __restrict__ wo,
                         const float* __restrict__ bo, float* __restrict__ out) {
    const int r0 = blockIdx.x * 16;
    __shared__ float xs[16][HID];
    for (int idx = threadIdx.x; idx < 16 * HID; idx += 256) {
        int r = idx >> 8;
        int k = idx & 255;
        xs[r][k] = ctx[(r0 + r) * HID + k];
    }
    __syncthreads();

    const int c = threadIdx.x;
    float acc[16];
#pragma unroll
    for (int r = 0; r < 16; r++) acc[r] = 0.f;

    const float4* wrow4 = reinterpret_cast<const float4*>(wo + c * HID);
    for (int k4 = 0; k4 < HID / 4; k4++) {
        float4 w4 = wrow4[k4];
        const int k = 4 * k4;
#pragma unroll
        for (int r = 0; r < 16; r++) {
            acc[r] = fmaf(xs[r][k + 0], w4.x, acc[r]);
            acc[r] = fmaf(xs[r][k + 1], w4.y, acc[r]);
            acc[r] = fmaf(xs[r][k + 2], w4.z, acc[r]);
            acc[r] = fmaf(xs[r][k + 3], w4.w, acc[r]);
        }
    }

    const float b = bo[c];
#pragma unroll
    for (int r = 0; r < 16; r++) {
        out[(r0 + r) * HID + c] = acc[r] + b;
    }
}

extern "C" void kernel_launch(void* const* d_in, const int* in_sizes, int n_in,
                              void* d_out, int out_size, void* d_ws, size_t ws_size,
                              hipStream_t stream) {
    const float* x  = (const float*)d_in[0];
    const float* wq = (const float*)d_in[1];
    const float* bq = (const float*)d_in[2];
    const float* wk = (const float*)d_in[3];
    const float* bk = (const float*)d_in[4];
    const float* wv = (const float*)d_in[5];
    const float* bv = (const float*)d_in[6];
    const float* wo = (const float*)d_in[7];
    const float* bo = (const float*)d_in[8];

    float* ws  = (float*)d_ws;
    float* ctx = ws + 524288;

    hipLaunchKernelGGL(proj_qkv, dim3(SEQ / 16, 3), dim3(256), 0, stream,
                       x, wq, bq, wk, bk, wv, bv, ws);
    hipLaunchKernelGGL(wave_attn, dim3(SEQ / 8, NH), dim3(256), 0, stream,
                       ws, ctx);
    hipLaunchKernelGGL(proj_out, dim3(SEQ / 16), dim3(256), 0, stream,
                       ctx, wo, bo, (float*)d_out);
}